// Round 12
// baseline (359.431 us; speedup 1.0000x reference)
//
#include <hip/hip_runtime.h>
#include <math.h>

#define NSIG 32768
#define KD   512
#define ED   64
#define SP   5

typedef double f64x4 __attribute__((ext_vector_type(4)));

// ---------------- prologue: DtD = Dt@D + eps*I  AND  zero coefOut ----------------
__global__ __launch_bounds__(256) void k_pre(const float* __restrict__ D,
                                             double* __restrict__ DtD,
                                             float4* __restrict__ coef4) {
  if (blockIdx.x < 1024) {
    int flat = blockIdx.x * 256 + threadIdx.x;   // 0..262143
    int i = flat >> 9, j = flat & 511;
    double acc = 0.0;
    #pragma unroll
    for (int e = 0; e < ED; ++e)
      acc += (double)D[e * KD + i] * (double)D[e * KD + j];
    if (i == j) acc += 1e-10;
    DtD[flat] = acc;
  } else {
    size_t count4 = (size_t)KD * NSIG / 4;
    size_t i = (size_t)(blockIdx.x - 1024) * 256 + threadIdx.x;
    size_t stride = (size_t)2048 * 256;
    float4 zv = make_float4(0.f, 0.f, 0.f, 0.f);
    for (; i < count4; i += stride) coef4[i] = zv;
  }
}

// ---------------- fused kernel: MFMA-f64 corr0 + per-signal OMP ----------------
// corr0 = Dt@z as f64 MFMA (v_mfma_f64_16x16x4): block = 16 signals, 8 waves;
//   wave w owns atoms 64w..64w+63 (4 16-atom tiles), K=64 in 16 steps of 4.
//   A[m][k]=D[e0+k][atom0+m] <- lane m+16k (from padded f32 LDS tile, cvt/lane)
//   B[k][n]=z[e0+k][sig n]   <- lane n+16k (from zbuf f32)
//   D/C: row=4*(lane>>4)+v, col(sig)=lane&15.
// Self-check: each lane verifies acc0[0] vs scalar recompute; any mismatch ->
//   block-uniform deterministic scalar fallback fill (correctness preserved).
// Transpose MFMA layout -> scan layout via 2-phase LDS (stride 258 f64).
// SCAN (omp_iter, unchanged): group (w,g) handles signal 2w+g; lane li owns
//   atoms {128*j4 + 4*li + bit}. Ginv triangle via Schur rank-1 (1 rcp/iter).
// cc_new = Ginv*c0sel - pad(cc_old)  (reference algebra: y = c0sel - G*pad(cc_old))
template <int K>
__device__ __forceinline__ void omp_iter(const double* __restrict__ DtD,
                                         const double (&c0)[16], unsigned& amask,
                                         int (&idx)[SP], double (&cc)[SP],
                                         double (&tri)[15], double (&c0sel)[SP],
                                         int li) {
  // ----- masked corr scan over this lane's 16 atoms (4 quads) -----
  double vb = -INFINITY;
  int ab = 0x7FFFFFFF;
  #pragma unroll
  for (int j4 = 0; j4 < 4; ++j4) {
    int a0 = (j4 << 7) + (li << 2);
    double v0 = c0[4 * j4], v1 = c0[4 * j4 + 1];
    double v2 = c0[4 * j4 + 2], v3 = c0[4 * j4 + 3];
    #pragma unroll
    for (int m = 0; m < K; ++m) {
      const double* gp = DtD + (size_t)idx[m] * KD + a0;
      double2 gA = *(const double2*)gp;
      double2 gB = *(const double2*)(gp + 2);
      v0 -= gA.x * cc[m];
      v1 -= gA.y * cc[m];
      v2 -= gB.x * cc[m];
      v3 -= gB.y * cc[m];
    }
    v0 = ((amask >> (4 * j4 + 0)) & 1u) ? -INFINITY : v0;
    v1 = ((amask >> (4 * j4 + 1)) & 1u) ? -INFINITY : v1;
    v2 = ((amask >> (4 * j4 + 2)) & 1u) ? -INFINITY : v2;
    v3 = ((amask >> (4 * j4 + 3)) & 1u) ? -INFINITY : v3;
    if (v0 > vb) { vb = v0; ab = a0; }        // ascending atoms per lane:
    if (v1 > vb) { vb = v1; ab = a0 + 1; }    // strict > keeps smallest on ties
    if (v2 > vb) { vb = v2; ab = a0 + 2; }
    if (v3 > vb) { vb = v3; ab = a0 + 3; }
  }
  // ----- 32-lane group argmax, tie-break: smallest atom (matches jnp.argmax) -----
  #pragma unroll
  for (int s = 16; s >= 1; s >>= 1) {
    double ov = __shfl_xor(vb, s, 64);
    int    oa = __shfl_xor(ab, s, 64);
    if (ov > vb || (ov == vb && oa < ab)) { vb = ov; ab = oa; }
  }
  idx[K] = ab;
  if (((ab >> 2) & 31) == li) amask |= 1u << ((((ab >> 7) << 2)) | (ab & 3));
  // ----- gather new Gram row entries (symmetric: also used to rebuild c0sel) -----
  const double* drow = DtD + (size_t)ab * KD;
  double bb[SP], u[SP];
  #pragma unroll
  for (int m = 0; m < K; ++m) bb[m] = drow[idx[m]];
  // c0sel[K] = corr0[ab] = vb + sum_m DtD[ab,idx_m]*cc_m  (symmetry: = bb[m])
  {
    double csel = vb;
    #pragma unroll
    for (int m = 0; m < K; ++m) csel += bb[m] * cc[m];
    c0sel[K] = csel;
  }
  // ----- Schur rank-1 update of Ginv triangle -----
  double sch = drow[ab];
  #pragma unroll
  for (int i = 0; i < K; ++i) {
    double ui = 0.0;
    #pragma unroll
    for (int m = 0; m < K; ++m) {
      int lo = i < m ? i : m, hi = i < m ? m : i;
      ui += tri[lo * SP - lo * (lo + 1) / 2 + hi] * bb[m];
    }
    u[i] = ui;
    sch -= bb[i] * ui;
  }
  double r = 1.0 / sch;
  #pragma unroll
  for (int i = 0; i < K; ++i) {
    #pragma unroll
    for (int j = i; j < K; ++j) tri[i * SP - i * (i + 1) / 2 + j] += r * u[i] * u[j];
    tri[i * SP - i * (i + 1) / 2 + K] = -r * u[i];
  }
  tri[K * SP - K * (K + 1) / 2 + K] = r;
  // ----- h = Ginv_new * c0sel ; cc = h - pad(cc_old) -----
  double h[SP];
  #pragma unroll
  for (int i = 0; i <= K; ++i) {
    double s = 0.0;
    #pragma unroll
    for (int j = 0; j <= K; ++j) {
      int lo = i < j ? i : j, hi = i < j ? j : i;
      s += tri[lo * SP - lo * (lo + 1) / 2 + hi] * c0sel[j];
    }
    h[i] = s;
  }
  #pragma unroll
  for (int i = 0; i < K; ++i) cc[i] = h[i] - cc[i];
  cc[K] = h[K];
}

__global__ __launch_bounds__(512) void k_fused(const float* __restrict__ z,
                                               const float* __restrict__ D,
                                               const double* __restrict__ DtD,
                                               float* __restrict__ coefOut,
                                               int* __restrict__ idxWs,
                                               double* __restrict__ cWs,
                                               double* __restrict__ csumWs) {
  // union region: Dlds (2 x 8 rows x 528 f32 padded = 33792 B) reused as
  // TR (16 sigs x 258 f64 = 33024 B) for the corr->scan transpose.
  __shared__ __align__(16) char ldsRaw[2 * 8 * 528 * 4];
  __shared__ float zbuf[64 * 16];    // 4 KB f32 [e][sig]
  __shared__ int badFlag;
  float* Dlds0 = (float*)ldsRaw;
  float* Dlds1 = (float*)ldsRaw + 8 * 528;
  double* TR = (double*)ldsRaw;

  int tid = threadIdx.x;
  int lane = tid & 63;
  int w = tid >> 6;                  // wave 0..7
  int li = lane & 31;
  int g  = lane >> 5;
  int arow = lane >> 4;              // 0..3 (k-index / row-block)
  int acol = lane & 15;              // 0..15 (atom-in-tile / signal)
  int sigBase = blockIdx.x * 16;
  int n = sigBase + 2 * w + g;       // this thread's scan signal

  // ---- stage z: zbuf[e*16+sig] = z[b, e, p0+sig] ----
  {
    int b = sigBase >> 10, p0 = sigBase & 1023;
    const float* zb = z + (size_t)b * 65536 + p0;
    #pragma unroll
    for (int k2 = 0; k2 < 2; ++k2) {
      int f = tid + 512 * k2;
      zbuf[f] = zb[(f >> 4) * 1024 + (f & 15)];
    }
  }
  if (tid == 0) badFlag = 0;

  // ---- stage D tile 0: wave w stages e-row w into padded row (528 f32) ----
  #pragma unroll
  for (int i = 0; i < 2; ++i) {
    const float* gp = D + (0 * 8 + w) * 512 + i * 256 + lane * 4;
    float* lp = Dlds0 + w * 528 + i * 256;
    __builtin_amdgcn_global_load_lds(
        (const __attribute__((address_space(1))) void*)gp,
        (__attribute__((address_space(3))) void*)lp, 16, 0, 0);
  }

  // ---- MFMA corr: acc_t = 16-atom tile t of wave w x 16 signals ----
  f64x4 acc0 = {0., 0., 0., 0.}, acc1 = {0., 0., 0., 0.};
  f64x4 acc2 = {0., 0., 0., 0.}, acc3 = {0., 0., 0., 0.};
  for (int t8 = 0; t8 < 8; ++t8) {
    __syncthreads();   // tile (t8&1) ready (drains gload_lds); other buf free
    if (t8 < 7) {
      #pragma unroll
      for (int i = 0; i < 2; ++i) {
        const float* gp = D + ((t8 + 1) * 8 + w) * 512 + i * 256 + lane * 4;
        float* lp = (((t8 + 1) & 1) ? Dlds1 : Dlds0) + w * 528 + i * 256;
        __builtin_amdgcn_global_load_lds(
            (const __attribute__((address_space(1))) void*)gp,
            (__attribute__((address_space(3))) void*)lp, 16, 0, 0);
      }
    }
    const float* buf = (t8 & 1) ? Dlds1 : Dlds0;
    #pragma unroll
    for (int ks = 0; ks < 2; ++ks) {
      int e0 = t8 * 8 + ks * 4;
      double bfrag = (double)zbuf[(e0 + arow) * 16 + acol];
      const float* ar = buf + (ks * 4 + arow) * 528 + 64 * w + acol;
      double a0 = (double)ar[0];
      double a1 = (double)ar[16];
      double a2 = (double)ar[32];
      double a3 = (double)ar[48];
      acc0 = __builtin_amdgcn_mfma_f64_16x16x4f64(a0, bfrag, acc0, 0, 0, 0);
      acc1 = __builtin_amdgcn_mfma_f64_16x16x4f64(a1, bfrag, acc1, 0, 0, 0);
      acc2 = __builtin_amdgcn_mfma_f64_16x16x4f64(a2, bfrag, acc2, 0, 0, 0);
      acc3 = __builtin_amdgcn_mfma_f64_16x16x4f64(a3, bfrag, acc3, 0, 0, 0);
    }
  }

  // ---- self-check: verify acc0[0] (atom 64w+4*arow, sig acol) vs scalar ----
  {
    int atomv = 64 * w + 4 * arow;
    double ref = 0.0;
    for (int e = 0; e < ED; ++e)
      ref += (double)D[e * KD + atomv] * (double)zbuf[e * 16 + acol];
    double diff = fabs(acc0[0] - ref);
    if (__any(diff > 1e-9 * fmax(1.0, fabs(ref)))) {
      if (lane == 0) badFlag = 1;
    }
  }
  __syncthreads();                   // Dlds consumed; badFlag visible
  bool bad = badFlag != 0;

  // ---- transpose phase A: atoms 0..255 -> TR[sig][atom], stride 258 ----
  if (!bad) {
    if (w < 4) {
      #pragma unroll
      for (int t = 0; t < 4; ++t) {
        const f64x4& a = (t == 0) ? acc0 : (t == 1) ? acc1 : (t == 2) ? acc2 : acc3;
        #pragma unroll
        for (int v = 0; v < 4; ++v) {
          int atomA = 64 * w + 16 * t + 4 * arow + v;
          TR[acol * 258 + atomA] = a[v];
        }
      }
    }
  } else {
    // deterministic scalar fallback fill (e-ascending, = vector reference)
    int s = tid & 15, a0b = (tid >> 4) * 8;
    for (int a = 0; a < 8; ++a) {
      double val = 0.0;
      for (int e = 0; e < ED; ++e)
        val += (double)D[e * KD + a0b + a] * (double)zbuf[e * 16 + s];
      TR[s * 258 + a0b + a] = val;
    }
  }
  __syncthreads();
  double c0[16];
  int myS = 2 * w + g;
  #pragma unroll
  for (int j4 = 0; j4 < 2; ++j4) {
    const double2* tp = (const double2*)(TR + myS * 258 + 128 * j4 + 4 * li);
    double2 q0 = tp[0], q1 = tp[1];
    c0[4 * j4 + 0] = q0.x; c0[4 * j4 + 1] = q0.y;
    c0[4 * j4 + 2] = q1.x; c0[4 * j4 + 3] = q1.y;
  }
  __syncthreads();
  // ---- transpose phase B: atoms 256..511 ----
  if (!bad) {
    if (w >= 4) {
      #pragma unroll
      for (int t = 0; t < 4; ++t) {
        const f64x4& a = (t == 0) ? acc0 : (t == 1) ? acc1 : (t == 2) ? acc2 : acc3;
        #pragma unroll
        for (int v = 0; v < 4; ++v) {
          int atomA = 64 * (w - 4) + 16 * t + 4 * arow + v;
          TR[acol * 258 + atomA] = a[v];
        }
      }
    }
  } else {
    int s = tid & 15, a0b = 256 + (tid >> 4) * 8;
    for (int a = 0; a < 8; ++a) {
      double val = 0.0;
      for (int e = 0; e < ED; ++e)
        val += (double)D[e * KD + a0b + a] * (double)zbuf[e * 16 + s];
      TR[s * 258 + a0b + a - 256] = val;
    }
  }
  __syncthreads();
  #pragma unroll
  for (int j4 = 2; j4 < 4; ++j4) {
    const double2* tp = (const double2*)(TR + myS * 258 + 128 * (j4 - 2) + 4 * li);
    double2 q0 = tp[0], q1 = tp[1];
    c0[4 * j4 + 0] = q0.x; c0[4 * j4 + 1] = q0.y;
    c0[4 * j4 + 2] = q1.x; c0[4 * j4 + 3] = q1.y;
  }

  // ---- OMP iterations (scan layout unchanged) ----
  unsigned amask = 0;
  int idx[SP]; double cc[SP]; double tri[15]; double c0sel[SP];
  omp_iter<0>(DtD, c0, amask, idx, cc, tri, c0sel, li);
  omp_iter<1>(DtD, c0, amask, idx, cc, tri, c0sel, li);
  omp_iter<2>(DtD, c0, amask, idx, cc, tri, c0sel, li);
  omp_iter<3>(DtD, c0, amask, idx, cc, tri, c0sel, li);
  omp_iter<4>(DtD, c0, amask, idx, cc, tri, c0sel, li);
  if (li == 0) {
    double cs = 0.0;
    #pragma unroll
    for (int j = 0; j < SP; ++j) {
      double cj = cc[j];
      cj = fmin(fmax(cj, -10000000.0), 10000000.0);   // COEFF_CLAMP
      cs += fabs(cj);
      idxWs[n * SP + j] = idx[j];
      cWs[n * SP + j] = cj;
      coefOut[(size_t)idx[j] * NSIG + n] = (float)cj;
    }
    csumWs[n] = cs;
  }
}

// ---------------- kernel D: z_q + per-block rec-loss partials ----------------
__global__ __launch_bounds__(256) void k_zq(const float* __restrict__ z,
                                            const float* __restrict__ D,
                                            const int* __restrict__ idxWs,
                                            const double* __restrict__ cWs,
                                            float* __restrict__ zqOut,
                                            double* __restrict__ recWs) {
  int t = threadIdx.x;
  size_t flat = (size_t)blockIdx.x * 256 + t;   // indexes z / z_q directly
  int b = (int)(flat >> 16);
  int e = (int)((flat >> 10) & 63);
  int p = (int)(flat & 1023);
  int n = b * 1024 + p;
  double u = 0.0;
  #pragma unroll
  for (int j = 0; j < SP; ++j) {
    int a = idxWs[n * SP + j];
    u += (double)D[e * KD + a] * cWs[n * SP + j];
  }
  float zv = z[flat];
  double d = u - (double)zv;
  double dc = fmin(fmax(d, -1.0), 1.0);
  zqOut[flat] = (float)((double)zv + dc);
  __shared__ double red[256];
  red[t] = d * d;
  __syncthreads();
  #pragma unroll
  for (int s = 128; s >= 1; s >>= 1) {
    if (t < s) red[t] += red[t + s];
    __syncthreads();
  }
  if (t == 0) recWs[blockIdx.x] = red[0];
}

// ---------------- kernel E: deterministic final reduction -> loss ----------------
__global__ __launch_bounds__(256) void k_loss(const double* __restrict__ recWs,
                                              const double* __restrict__ csumWs,
                                              float* __restrict__ lossOut) {
  int t = threadIdx.x;
  double r = 0.0, c = 0.0;
  for (int i = t; i < 8192; i += 256) r += recWs[i];
  for (int i = t; i < NSIG; i += 256) c += csumWs[i];
  __shared__ double red[512];
  red[t] = r; red[256 + t] = c;
  __syncthreads();
  #pragma unroll
  for (int s = 128; s >= 1; s >>= 1) {
    if (t < s) { red[t] += red[t + s]; red[256 + t] += red[256 + t + s]; }
    __syncthreads();
  }
  if (t == 0) {
    double rec = red[0] / (double)(64.0 * 32768.0);
    double cm  = red[256] / (double)(512.0 * 32768.0);
    // loss = rec + 0.25*(1+5/10)*commit + 1e-3*coeff ; commit == rec numerically
    double loss = rec + 0.375 * rec + 0.001 * cm;
    lossOut[0] = (float)loss;
  }
}

extern "C" void kernel_launch(void* const* d_in, const int* in_sizes, int n_in,
                              void* d_out, int out_size, void* d_ws, size_t ws_size,
                              hipStream_t stream) {
  const float* z = (const float*)d_in[0];       // (32,64,32,32)
  const float* D = (const float*)d_in[1];       // (64,512)
  float* out = (float*)d_out;
  float* zqOut   = out;                         // 2097152
  float* lossOut = out + 2097152;               // 1
  float* coefOut = out + 2097153;               // 512*32768

  // workspace carve (all 8B-aligned offsets)
  char* w = (char*)d_ws;
  double* DtD    = (double*)w; w += (size_t)KD * KD * 8;        // 2 MB
  int*    idxWs  = (int*)w;    w += (size_t)NSIG * SP * 4;      // 640 KB
  double* cWs    = (double*)w; w += (size_t)NSIG * SP * 8;      // 1.25 MB
  double* csumWs = (double*)w; w += (size_t)NSIG * 8;           // 256 KB
  double* recWs  = (double*)w; w += (size_t)8192 * 8;           // 64 KB

  k_pre<<<3072, 256, 0, stream>>>(D, DtD, (float4*)coefOut);
  k_fused<<<NSIG / 16, 512, 0, stream>>>(z, D, DtD, coefOut, idxWs, cWs, csumWs);
  k_zq<<<8192, 256, 0, stream>>>(z, D, idxWs, cWs, zqOut, recWs);
  k_loss<<<1, 256, 0, stream>>>(recWs, csumWs, lossOut);
}